// Round 11
// baseline (121.362 us; speedup 1.0000x reference)
//
#include <hip/hip_runtime.h>
#include <hip/hip_bf16.h>

#define N_ROWS 32768
#define K_DIM 512
#define OUT_DIM 512
#define N_TYPES 8
#define NB 520              // max 64-row blocks after per-type padding
#define BM 64
#define BN 128
#define BK 64
#define NT (K_DIM / BK)     // 8 K-steps

typedef __attribute__((ext_vector_type(8))) short bf16x8;
typedef __attribute__((ext_vector_type(4))) float f32x4;

__device__ inline ushort f2bf(float f) {
    __hip_bfloat16 h = __float2bfloat16(f);
    return *reinterpret_cast<ushort*>(&h);
}

__device__ inline void gload_lds16(const void* g, void* l) {
    __builtin_amdgcn_global_load_lds(
        (const __attribute__((address_space(1))) void*)g,
        (__attribute__((address_space(3))) void*)l, 16, 0, 0);
}

// meta layout (ints): [0..7] counts, [8..15] padded bases, [16] padded total,
//                     [20..27] cursors
__global__ void k_init(int* meta) {
    if (threadIdx.x < 32) meta[threadIdx.x] = 0;
}

__global__ void k_hist(const int* __restrict__ x_type, int* meta) {
    __shared__ int cnt[N_TYPES];
    if (threadIdx.x < N_TYPES) cnt[threadIdx.x] = 0;
    __syncthreads();
    int i = blockIdx.x * 256 + threadIdx.x;
    atomicAdd(&cnt[x_type[i]], 1);
    __syncthreads();
    if (threadIdx.x < N_TYPES && cnt[threadIdx.x] > 0)
        atomicAdd(&meta[threadIdx.x], cnt[threadIdx.x]);
}

__global__ void k_scan(int* meta) {
    if (threadIdx.x == 0) {
        int s = 0;
        for (int t = 0; t < N_TYPES; ++t) {
            meta[8 + t]  = s;      // padded base
            meta[20 + t] = s;      // cursor
            s += (meta[t] + 63) & ~63;   // pad each type segment to 64
        }
        meta[16] = s;              // padded total
    }
}

// per-block LDS hist -> reserve range with 8 global atomics -> scatter
// (row_ids pre-filled with -1; pad slots stay -1)
__global__ void k_fill(const int* __restrict__ x_type, int* meta, int* __restrict__ row_ids) {
    __shared__ int lcnt[N_TYPES];
    __shared__ int lbase[N_TYPES];
    if (threadIdx.x < N_TYPES) lcnt[threadIdx.x] = 0;
    __syncthreads();
    int i = blockIdx.x * 256 + threadIdx.x;
    int t = x_type[i];
    int lpos = atomicAdd(&lcnt[t], 1);
    __syncthreads();
    if (threadIdx.x < N_TYPES)
        lbase[threadIdx.x] = (lcnt[threadIdx.x] > 0)
            ? atomicAdd(&meta[20 + threadIdx.x], lcnt[threadIdx.x]) : 0;
    __syncthreads();
    row_ids[lbase[t] + lpos] = i;
}

// W[t][k][c] fp32 -> Wt[t][c][k] bf16   (64x64 tiles through LDS)
__global__ void k_wt(const float* __restrict__ W, ushort* __restrict__ Wt) {
    __shared__ float tile[64][65];
    int t = blockIdx.x, kb = blockIdx.y, cb = blockIdx.z;
    const float* src = W + (size_t)t * K_DIM * OUT_DIM + (size_t)kb * 64 * OUT_DIM + cb * 64;
    #pragma unroll
    for (int j = 0; j < 16; ++j) {
        int idx = threadIdx.x + j * 256;
        int r = idx >> 6, c = idx & 63;
        tile[r][c] = src[(size_t)r * OUT_DIM + c];
    }
    __syncthreads();
    ushort* dst = Wt + (size_t)t * OUT_DIM * K_DIM + (size_t)(cb * 64) * K_DIM + kb * 64;
    #pragma unroll
    for (int j = 0; j < 16; ++j) {
        int idx = threadIdx.x + j * 256;
        int cc = idx >> 6, kk = idx & 63;
        dst[(size_t)cc * K_DIM + kk] = f2bf(tile[kk][cc]);
    }
}

// Round-6 structure at half block size: 64x128 tile, 256 thr (4 waves of
// 32x64 out, acc[2][4]), BK=64 single-buffered, LDS 24.25 KB -> 6 blocks/CU
// (vs r6's 3) for 2x barrier-stagger at the same 24 waves/CU.
// Proven involution swizzle (0 conflicts): byte granule g ^= (id&7) within
// 128-B rows; B staged by global_load_lds with the involution folded into
// the per-lane SOURCE (linear dest, rule #21); A reg-staged fp32->bf16.
__global__ __launch_bounds__(256, 6) void k_gemm10(
    const float* __restrict__ x, const ushort* __restrict__ Wt,
    const int* __restrict__ meta, const int* __restrict__ row_ids,
    float* __restrict__ out) {

    __shared__ ushort As[BM * BK];   // 8192 B,  [row][64k], 128 B/row
    __shared__ ushort Bs[BN * BK];   // 16384 B, [col][64k], 128 B/col-row
    __shared__ int rids[BM];

    int b = blockIdx.x;              // row-blocks fastest -> x L3-absorbed
    int r0 = b * BM;
    if (r0 >= meta[16]) return;
    int type = 0;
    #pragma unroll
    for (int t = 0; t < N_TYPES; ++t)
        if (r0 >= meta[8 + t]) type = t;

    int tid = threadIdx.x;
    int wave = tid >> 6, lane = tid & 63;

    if (tid < BM) rids[tid] = row_ids[r0 + tid];
    __syncthreads();

    int c0 = blockIdx.y * BN;
    const ushort* Wtt = Wt + (size_t)type * OUT_DIM * K_DIM + (size_t)c0 * K_DIM;

    // ---- A staging role: 4 threads/row, 16 elems (2 granules) each ----
    int sa_row  = tid >> 2;
    int sa_slot = tid & 3;           // which 16-elem quarter of the 64-k row
    int sa_rid  = rids[sa_row];
    const float* sa_src = x + (size_t)max(sa_rid, 0) * K_DIM + sa_slot * 16;

    // ---- B staging role: chunk = 8 cols x 128 B (1 KB); lane -> (col,pos);
    //      source granule = pos ^ (col&7)  (involution on SOURCE) ----
    int sb_col  = lane >> 3;         // col within chunk (0..7)
    int sb_p    = lane & 7;          // dest granule position
    int sb_srcg = sb_p ^ sb_col;     // col&7 == sb_col (chunk*8 is mult of 8)

    int wrb = (wave & 1) * 32;       // wave row base (0/32)
    int wcb = (wave >> 1) * 64;      // wave col base (0/64)
    int lrow = lane & 15;
    int g16  = lane >> 4;            // k-granule within 32-k half (0..3)

    f32x4 acc[2][4] = {};

    #pragma unroll 2
    for (int t8 = 0; t8 < NT; ++t8) {
        int kk = t8 * BK;
        // ---- stage B: 4 chunks/wave (16 chunks = 128 cols) ----
        #pragma unroll
        for (int j = 0; j < 4; ++j) {
            int chunk = wave * 4 + j;
            int col = chunk * 8 + sb_col;
            gload_lds16(Wtt + (size_t)col * K_DIM + kk + sb_srcg * 8,
                        (char*)Bs + chunk * 1024);
        }
        // ---- stage A: 16 fp32 -> 16 bf16, 2 swizzled ds_write_b128 ----
        {
            float4 v[4];
            #pragma unroll
            for (int q = 0; q < 4; ++q)
                v[q] = (sa_rid >= 0)
                    ? *reinterpret_cast<const float4*>(sa_src + kk + q * 4)
                    : float4{0.f, 0.f, 0.f, 0.f};
            #pragma unroll
            for (int q = 0; q < 2; ++q) {
                ushort tmp[8] = {
                    f2bf(v[q*2].x),   f2bf(v[q*2].y),   f2bf(v[q*2].z),   f2bf(v[q*2].w),
                    f2bf(v[q*2+1].x), f2bf(v[q*2+1].y), f2bf(v[q*2+1].z), f2bf(v[q*2+1].w) };
                int p = sa_slot * 2 + q;
                int byte = sa_row * 128 + ((p ^ (sa_row & 7)) * 16);
                *reinterpret_cast<uint4*>((char*)As + byte) =
                    *reinterpret_cast<const uint4*>(tmp);
            }
        }
        __syncthreads();

        // ---- compute: 2 k-halves x 8 MFMA (16 MFMA, 12 ds_read_b128) ----
        #pragma unroll
        for (int s = 0; s < 2; ++s) {
            int g = s * 4 + g16;
            bf16x8 af[2], bfr[4];
            #pragma unroll
            for (int mi = 0; mi < 2; ++mi) {
                int row = wrb + mi * 16 + lrow;
                int byte = row * 128 + ((g ^ (row & 7)) * 16);
                af[mi] = *reinterpret_cast<const bf16x8*>((const char*)As + byte);
            }
            #pragma unroll
            for (int ni = 0; ni < 4; ++ni) {
                int col = wcb + ni * 16 + lrow;
                int byte = col * 128 + ((g ^ (col & 7)) * 16);
                bfr[ni] = *reinterpret_cast<const bf16x8*>((const char*)Bs + byte);
            }
            #pragma unroll
            for (int mi = 0; mi < 2; ++mi)
                #pragma unroll
                for (int ni = 0; ni < 4; ++ni)
                    acc[mi][ni] = __builtin_amdgcn_mfma_f32_16x16x32_bf16(
                        af[mi], bfr[ni], acc[mi][ni], 0, 0, 0);
        }
        __syncthreads();
    }

    // epilogue: D row = (lane>>4)*4 + rr, col = lane&15
    int rgrp = g16 * 4;
    #pragma unroll
    for (int mi = 0; mi < 2; ++mi) {
        #pragma unroll
        for (int rr = 0; rr < 4; ++rr) {
            int lr = wrb + mi * 16 + rgrp + rr;
            int gr = rids[lr];
            if (gr >= 0) {
                float* dst = out + (size_t)gr * OUT_DIM + c0 + wcb;
                #pragma unroll
                for (int ni = 0; ni < 4; ++ni)
                    dst[ni * 16 + lrow] = acc[mi][ni][rr];
            }
        }
    }
}

extern "C" void kernel_launch(void* const* d_in, const int* in_sizes, int n_in,
                              void* d_out, int out_size, void* d_ws, size_t ws_size,
                              hipStream_t stream) {
    const float* x      = (const float*)d_in[0];
    const int*   x_type = (const int*)d_in[1];
    const float* W      = (const float*)d_in[2];
    float* out          = (float*)d_out;

    char* ws = (char*)d_ws;
    size_t off_rids = 256;
    size_t off_wt   = off_rids + sizeof(int) * (NB * 64);
    int* meta    = (int*)ws;
    int* row_ids = (int*)(ws + off_rids);
    ushort* Wt   = (ushort*)(ws + off_wt);                  // 4 MB bf16

    k_init<<<1, 64, 0, stream>>>(meta);
    k_hist<<<N_ROWS / 256, 256, 0, stream>>>(x_type, meta);
    k_scan<<<1, 64, 0, stream>>>(meta);
    hipMemsetAsync(row_ids, 0xFF, sizeof(int) * (NB * 64), stream);
    k_fill<<<N_ROWS / 256, 256, 0, stream>>>(x_type, meta, row_ids);

    dim3 wgrid(N_TYPES, K_DIM / 64, OUT_DIM / 64);
    k_wt<<<wgrid, 256, 0, stream>>>(W, Wt);

    // row-blocks fastest: the 4 column passes over x (64 MB, L3-fits)
    // come a full pass apart -> L3-absorbed (r10 evidence: 85 MB FETCH)
    dim3 ggrid(NB, OUT_DIM / BN);
    k_gemm10<<<ggrid, 256, 0, stream>>>(x, Wt, meta, row_ids, out);
}

// Round 12
// 84.716 us; speedup vs baseline: 1.4326x; 1.4326x over previous
//
#include <hip/hip_runtime.h>
#include <hip/hip_bf16.h>

#define N_ROWS 32768
#define K_DIM 512
#define OUT_DIM 512
#define N_TYPES 8
#define NB 520              // max 64-row blocks after per-type padding
#define BM 64
#define BN 128
#define BK 64
#define NT (K_DIM / BK)     // 8 K-steps

typedef __attribute__((ext_vector_type(8))) short bf16x8;
typedef __attribute__((ext_vector_type(4))) float f32x4;

__device__ inline ushort f2bf(float f) {
    __hip_bfloat16 h = __float2bfloat16(f);
    return *reinterpret_cast<ushort*>(&h);
}

__device__ inline void gload_lds16(const void* g, void* l) {
    __builtin_amdgcn_global_load_lds(
        (const __attribute__((address_space(1))) void*)g,
        (__attribute__((address_space(3))) void*)l, 16, 0, 0);
}

// meta layout (ints): [0..7] counts, [8..15] padded bases, [16] padded total,
//                     [20..27] cursors
__global__ void k_init(int* meta) {
    if (threadIdx.x < 32) meta[threadIdx.x] = 0;
}

__global__ void k_hist(const int* __restrict__ x_type, int* meta) {
    __shared__ int cnt[N_TYPES];
    if (threadIdx.x < N_TYPES) cnt[threadIdx.x] = 0;
    __syncthreads();
    int i = blockIdx.x * 256 + threadIdx.x;
    atomicAdd(&cnt[x_type[i]], 1);
    __syncthreads();
    if (threadIdx.x < N_TYPES && cnt[threadIdx.x] > 0)
        atomicAdd(&meta[threadIdx.x], cnt[threadIdx.x]);
}

__global__ void k_scan(int* meta) {
    if (threadIdx.x == 0) {
        int s = 0;
        for (int t = 0; t < N_TYPES; ++t) {
            meta[8 + t]  = s;      // padded base
            meta[20 + t] = s;      // cursor
            s += (meta[t] + 63) & ~63;   // pad each type segment to 64
        }
        meta[16] = s;              // padded total
    }
}

// per-block LDS hist -> reserve range with 8 global atomics -> scatter
// (row_ids pre-filled with -1; pad slots stay -1)
__global__ void k_fill(const int* __restrict__ x_type, int* meta, int* __restrict__ row_ids) {
    __shared__ int lcnt[N_TYPES];
    __shared__ int lbase[N_TYPES];
    if (threadIdx.x < N_TYPES) lcnt[threadIdx.x] = 0;
    __syncthreads();
    int i = blockIdx.x * 256 + threadIdx.x;
    int t = x_type[i];
    int lpos = atomicAdd(&lcnt[t], 1);
    __syncthreads();
    if (threadIdx.x < N_TYPES)
        lbase[threadIdx.x] = (lcnt[threadIdx.x] > 0)
            ? atomicAdd(&meta[20 + threadIdx.x], lcnt[threadIdx.x]) : 0;
    __syncthreads();
    row_ids[lbase[t] + lpos] = i;
}

// W[t][k][c] fp32 -> Wt[t][c][k] bf16   (64x64 tiles through LDS)
__global__ void k_wt(const float* __restrict__ W, ushort* __restrict__ Wt) {
    __shared__ float tile[64][65];
    int t = blockIdx.x, kb = blockIdx.y, cb = blockIdx.z;
    const float* src = W + (size_t)t * K_DIM * OUT_DIM + (size_t)kb * 64 * OUT_DIM + cb * 64;
    #pragma unroll
    for (int j = 0; j < 16; ++j) {
        int idx = threadIdx.x + j * 256;
        int r = idx >> 6, c = idx & 63;
        tile[r][c] = src[(size_t)r * OUT_DIM + c];
    }
    __syncthreads();
    ushort* dst = Wt + (size_t)t * OUT_DIM * K_DIM + (size_t)(cb * 64) * K_DIM + kb * 64;
    #pragma unroll
    for (int j = 0; j < 16; ++j) {
        int idx = threadIdx.x + j * 256;
        int cc = idx >> 6, kk = idx & 63;
        dst[(size_t)cc * K_DIM + kk] = f2bf(tile[kk][cc]);
    }
}

// Round-11 kernel with ONE change: __launch_bounds__(256, 4) so the VGPR
// allocator gets 128 regs (kernel needs ~100) -> NO SCRATCH SPILL.
// r11's (256,6) capped at 85 VGPRs -> inner-loop spills: VGPR_Count=40,
// WRITE_SIZE 156 MB (out is 64 MB), FETCH 183 MB, MfmaUtil 5%.
// Occupancy: min(LDS 160/24.5=6, VGPR 512/~100=5) ~= 5 blocks/CU.
__global__ __launch_bounds__(256, 4) void k_gemm11(
    const float* __restrict__ x, const ushort* __restrict__ Wt,
    const int* __restrict__ meta, const int* __restrict__ row_ids,
    float* __restrict__ out) {

    __shared__ ushort As[BM * BK];   // 8192 B,  [row][64k], 128 B/row
    __shared__ ushort Bs[BN * BK];   // 16384 B, [col][64k], 128 B/col-row
    __shared__ int rids[BM];

    int b = blockIdx.x;              // row-blocks fastest -> x L3-absorbed
    int r0 = b * BM;
    if (r0 >= meta[16]) return;
    int type = 0;
    #pragma unroll
    for (int t = 0; t < N_TYPES; ++t)
        if (r0 >= meta[8 + t]) type = t;

    int tid = threadIdx.x;
    int wave = tid >> 6, lane = tid & 63;

    if (tid < BM) rids[tid] = row_ids[r0 + tid];
    __syncthreads();

    int c0 = blockIdx.y * BN;
    const ushort* Wtt = Wt + (size_t)type * OUT_DIM * K_DIM + (size_t)c0 * K_DIM;

    // ---- A staging role: 4 threads/row, 16 elems (2 granules) each ----
    int sa_row  = tid >> 2;
    int sa_slot = tid & 3;           // which 16-elem quarter of the 64-k row
    int sa_rid  = rids[sa_row];
    const float* sa_src = x + (size_t)max(sa_rid, 0) * K_DIM + sa_slot * 16;

    // ---- B staging role: chunk = 8 cols x 128 B (1 KB); lane -> (col,pos);
    //      source granule = pos ^ (col&7)  (involution on SOURCE) ----
    int sb_col  = lane >> 3;         // col within chunk (0..7)
    int sb_p    = lane & 7;          // dest granule position
    int sb_srcg = sb_p ^ sb_col;     // col&7 == sb_col (chunk*8 is mult of 8)

    int wrb = (wave & 1) * 32;       // wave row base (0/32)
    int wcb = (wave >> 1) * 64;      // wave col base (0/64)
    int lrow = lane & 15;
    int g16  = lane >> 4;            // k-granule within 32-k half (0..3)

    f32x4 acc[2][4] = {};

    #pragma unroll 2
    for (int t8 = 0; t8 < NT; ++t8) {
        int kk = t8 * BK;
        // ---- stage B: 4 chunks/wave (16 chunks = 128 cols) ----
        #pragma unroll
        for (int j = 0; j < 4; ++j) {
            int chunk = wave * 4 + j;
            int col = chunk * 8 + sb_col;
            gload_lds16(Wtt + (size_t)col * K_DIM + kk + sb_srcg * 8,
                        (char*)Bs + chunk * 1024);
        }
        // ---- stage A: 16 fp32 -> 16 bf16, 2 swizzled ds_write_b128 ----
        {
            float4 v[4];
            #pragma unroll
            for (int q = 0; q < 4; ++q)
                v[q] = (sa_rid >= 0)
                    ? *reinterpret_cast<const float4*>(sa_src + kk + q * 4)
                    : float4{0.f, 0.f, 0.f, 0.f};
            #pragma unroll
            for (int q = 0; q < 2; ++q) {
                ushort tmp[8] = {
                    f2bf(v[q*2].x),   f2bf(v[q*2].y),   f2bf(v[q*2].z),   f2bf(v[q*2].w),
                    f2bf(v[q*2+1].x), f2bf(v[q*2+1].y), f2bf(v[q*2+1].z), f2bf(v[q*2+1].w) };
                int p = sa_slot * 2 + q;
                int byte = sa_row * 128 + ((p ^ (sa_row & 7)) * 16);
                *reinterpret_cast<uint4*>((char*)As + byte) =
                    *reinterpret_cast<const uint4*>(tmp);
            }
        }
        __syncthreads();

        // ---- compute: 2 k-halves x 8 MFMA (16 MFMA, 12 ds_read_b128) ----
        #pragma unroll
        for (int s = 0; s < 2; ++s) {
            int g = s * 4 + g16;
            bf16x8 af[2], bfr[4];
            #pragma unroll
            for (int mi = 0; mi < 2; ++mi) {
                int row = wrb + mi * 16 + lrow;
                int byte = row * 128 + ((g ^ (row & 7)) * 16);
                af[mi] = *reinterpret_cast<const bf16x8*>((const char*)As + byte);
            }
            #pragma unroll
            for (int ni = 0; ni < 4; ++ni) {
                int col = wcb + ni * 16 + lrow;
                int byte = col * 128 + ((g ^ (col & 7)) * 16);
                bfr[ni] = *reinterpret_cast<const bf16x8*>((const char*)Bs + byte);
            }
            #pragma unroll
            for (int mi = 0; mi < 2; ++mi)
                #pragma unroll
                for (int ni = 0; ni < 4; ++ni)
                    acc[mi][ni] = __builtin_amdgcn_mfma_f32_16x16x32_bf16(
                        af[mi], bfr[ni], acc[mi][ni], 0, 0, 0);
        }
        __syncthreads();
    }

    // epilogue: D row = (lane>>4)*4 + rr, col = lane&15
    int rgrp = g16 * 4;
    #pragma unroll
    for (int mi = 0; mi < 2; ++mi) {
        #pragma unroll
        for (int rr = 0; rr < 4; ++rr) {
            int lr = wrb + mi * 16 + rgrp + rr;
            int gr = rids[lr];
            if (gr >= 0) {
                float* dst = out + (size_t)gr * OUT_DIM + c0 + wcb;
                #pragma unroll
                for (int ni = 0; ni < 4; ++ni)
                    dst[ni * 16 + lrow] = acc[mi][ni][rr];
            }
        }
    }
}

extern "C" void kernel_launch(void* const* d_in, const int* in_sizes, int n_in,
                              void* d_out, int out_size, void* d_ws, size_t ws_size,
                              hipStream_t stream) {
    const float* x      = (const float*)d_in[0];
    const int*   x_type = (const int*)d_in[1];
    const float* W      = (const float*)d_in[2];
    float* out          = (float*)d_out;

    char* ws = (char*)d_ws;
    size_t off_rids = 256;
    size_t off_wt   = off_rids + sizeof(int) * (NB * 64);
    int* meta    = (int*)ws;
    int* row_ids = (int*)(ws + off_rids);
    ushort* Wt   = (ushort*)(ws + off_wt);                  // 4 MB bf16

    k_init<<<1, 64, 0, stream>>>(meta);
    k_hist<<<N_ROWS / 256, 256, 0, stream>>>(x_type, meta);
    k_scan<<<1, 64, 0, stream>>>(meta);
    hipMemsetAsync(row_ids, 0xFF, sizeof(int) * (NB * 64), stream);
    k_fill<<<N_ROWS / 256, 256, 0, stream>>>(x_type, meta, row_ids);

    dim3 wgrid(N_TYPES, K_DIM / 64, OUT_DIM / 64);
    k_wt<<<wgrid, 256, 0, stream>>>(W, Wt);

    // row-blocks fastest: the 4 column passes over x (64 MB, L3-fits)
    // come a full pass apart -> L3-absorbed (r10 evidence: 85 MB FETCH)
    dim3 ggrid(NB, OUT_DIM / BN);
    k_gemm11<<<ggrid, 256, 0, stream>>>(x, Wt, meta, row_ids, out);
}

// Round 13
// 81.039 us; speedup vs baseline: 1.4976x; 1.0454x over previous
//
#include <hip/hip_runtime.h>
#include <hip/hip_bf16.h>

#define N_ROWS 32768
#define K_DIM 512
#define OUT_DIM 512
#define N_TYPES 8
#define NB 520              // max 64-row blocks after per-type padding
#define BM 64
#define BN 128
#define BK 64
#define NT (K_DIM / BK)     // 8 K-steps
#define ABUF 8192           // bytes per A buffer = 64 rows x 128 B
#define BBUF 16384          // bytes per B buffer = 128 cols x 128 B

typedef __attribute__((ext_vector_type(8))) short bf16x8;
typedef __attribute__((ext_vector_type(4))) float f32x4;

__device__ inline ushort f2bf(float f) {
    __hip_bfloat16 h = __float2bfloat16(f);
    return *reinterpret_cast<ushort*>(&h);
}

__device__ inline void gload_lds16(const void* g, void* l) {
    __builtin_amdgcn_global_load_lds(
        (const __attribute__((address_space(1))) void*)g,
        (__attribute__((address_space(3))) void*)l, 16, 0, 0);
}

// meta layout (ints): [0..7] counts, [8..15] padded bases, [16] padded total,
//                     [20..27] cursors
__global__ void k_init(int* meta) {
    if (threadIdx.x < 32) meta[threadIdx.x] = 0;
}

__global__ void k_hist(const int* __restrict__ x_type, int* meta) {
    __shared__ int cnt[N_TYPES];
    if (threadIdx.x < N_TYPES) cnt[threadIdx.x] = 0;
    __syncthreads();
    int i = blockIdx.x * 256 + threadIdx.x;
    atomicAdd(&cnt[x_type[i]], 1);
    __syncthreads();
    if (threadIdx.x < N_TYPES && cnt[threadIdx.x] > 0)
        atomicAdd(&meta[threadIdx.x], cnt[threadIdx.x]);
}

__global__ void k_scan(int* meta) {
    if (threadIdx.x == 0) {
        int s = 0;
        for (int t = 0; t < N_TYPES; ++t) {
            meta[8 + t]  = s;      // padded base
            meta[20 + t] = s;      // cursor
            s += (meta[t] + 63) & ~63;   // pad each type segment to 64
        }
        meta[16] = s;              // padded total
    }
}

// per-block LDS hist -> reserve range with 8 global atomics -> scatter
// (row_ids pre-filled with -1; pad slots stay -1)
__global__ void k_fill(const int* __restrict__ x_type, int* meta, int* __restrict__ row_ids) {
    __shared__ int lcnt[N_TYPES];
    __shared__ int lbase[N_TYPES];
    if (threadIdx.x < N_TYPES) lcnt[threadIdx.x] = 0;
    __syncthreads();
    int i = blockIdx.x * 256 + threadIdx.x;
    int t = x_type[i];
    int lpos = atomicAdd(&lcnt[t], 1);
    __syncthreads();
    if (threadIdx.x < N_TYPES)
        lbase[threadIdx.x] = (lcnt[threadIdx.x] > 0)
            ? atomicAdd(&meta[20 + threadIdx.x], lcnt[threadIdx.x]) : 0;
    __syncthreads();
    row_ids[lbase[t] + lpos] = i;
}

// W[t][k][c] fp32 -> Wt[t][c][k] bf16   (64x64 tiles through LDS)
__global__ void k_wt(const float* __restrict__ W, ushort* __restrict__ Wt) {
    __shared__ float tile[64][65];
    int t = blockIdx.x, kb = blockIdx.y, cb = blockIdx.z;
    const float* src = W + (size_t)t * K_DIM * OUT_DIM + (size_t)kb * 64 * OUT_DIM + cb * 64;
    #pragma unroll
    for (int j = 0; j < 16; ++j) {
        int idx = threadIdx.x + j * 256;
        int r = idx >> 6, c = idx & 63;
        tile[r][c] = src[(size_t)r * OUT_DIM + c];
    }
    __syncthreads();
    ushort* dst = Wt + (size_t)t * OUT_DIM * K_DIM + (size_t)(cb * 64) * K_DIM + kb * 64;
    #pragma unroll
    for (int j = 0; j < 16; ++j) {
        int idx = threadIdx.x + j * 256;
        int cc = idx >> 6, kk = idx & 63;
        dst[(size_t)cc * K_DIM + kk] = f2bf(tile[kk][cc]);
    }
}

// 64x128 tile, 256 thr (4 waves of 32x64 out, acc[2][4]), BK=64,
// DOUBLE-buffered 2-phase: stage(t+1) issued BEFORE compute(t), A ds_write
// after compute (T14), ONE __syncthreads per K-step -> the compiler's
// vmcnt(0)-before-barrier drain lands after 16 MFMA + 12 ds_read of cover.
// LDS = 2x8 + 2x16 = 48.25 KB -> 3 blocks/CU.  (256,4) -> no spill (r12).
// Proven involution swizzle (0 conflicts): granule g ^= (id&7) in 128-B rows;
// B via global_load_lds, involution folded into per-lane SOURCE (rule #21).
__global__ __launch_bounds__(256, 4) void k_gemm12(
    const float* __restrict__ x, const ushort* __restrict__ Wt,
    const int* __restrict__ meta, const int* __restrict__ row_ids,
    float* __restrict__ out) {

    __shared__ ushort As[2 * BM * BK];   // 16384 B total, ABUF=8192 per buf
    __shared__ ushort Bs[2 * BN * BK];   // 32768 B total, BBUF=16384 per buf
    __shared__ int rids[BM];

    int b = blockIdx.x;              // row-blocks fastest -> x L3-absorbed
    int r0 = b * BM;
    if (r0 >= meta[16]) return;
    int type = 0;
    #pragma unroll
    for (int t = 0; t < N_TYPES; ++t)
        if (r0 >= meta[8 + t]) type = t;

    int tid = threadIdx.x;
    int wave = tid >> 6, lane = tid & 63;

    if (tid < BM) rids[tid] = row_ids[r0 + tid];
    __syncthreads();

    int c0 = blockIdx.y * BN;
    const ushort* Wtt = Wt + (size_t)type * OUT_DIM * K_DIM + (size_t)c0 * K_DIM;

    // ---- A staging role: 4 threads/row, 16 elems (2 granules) each ----
    int sa_row  = tid >> 2;
    int sa_slot = tid & 3;           // which 16-elem quarter of the 64-k row
    int sa_rid  = rids[sa_row];
    const float* sa_src = x + (size_t)max(sa_rid, 0) * K_DIM + sa_slot * 16;

    // ---- B staging role: chunk = 8 cols x 128 B (1 KB); lane -> (col,pos);
    //      source granule = pos ^ (col&7)  (involution on SOURCE) ----
    int sb_col  = lane >> 3;         // col within chunk (0..7)
    int sb_p    = lane & 7;          // dest granule position
    int sb_srcg = sb_p ^ sb_col;     // col&7 == sb_col (chunk*8 is mult of 8)

    int wrb = (wave & 1) * 32;       // wave row base (0/32)
    int wcb = (wave >> 1) * 64;      // wave col base (0/64)
    int lrow = lane & 15;
    int g16  = lane >> 4;            // k-granule within 32-k half (0..3)

    f32x4 acc[2][4] = {};

#define STAGE_B(buf, t)                                                         \
    _Pragma("unroll")                                                           \
    for (int j = 0; j < 4; ++j) {                                               \
        int chunk = wave * 4 + j;                                               \
        int col = chunk * 8 + sb_col;                                           \
        gload_lds16(Wtt + (size_t)col * K_DIM + (t) * BK + sb_srcg * 8,         \
                    (char*)Bs + (buf) * BBUF + chunk * 1024);                   \
    }

#define LOAD_X(t, v)                                                            \
    _Pragma("unroll")                                                           \
    for (int q = 0; q < 4; ++q)                                                 \
        v[q] = (sa_rid >= 0)                                                    \
            ? *reinterpret_cast<const float4*>(sa_src + (t) * BK + q * 4)       \
            : float4{0.f, 0.f, 0.f, 0.f};

#define WRITE_A(buf, v)                                                         \
    _Pragma("unroll")                                                           \
    for (int q = 0; q < 2; ++q) {                                               \
        ushort tmp[8] = {                                                       \
            f2bf(v[q*2].x),   f2bf(v[q*2].y),   f2bf(v[q*2].z),   f2bf(v[q*2].w), \
            f2bf(v[q*2+1].x), f2bf(v[q*2+1].y), f2bf(v[q*2+1].z), f2bf(v[q*2+1].w) }; \
        int p = sa_slot * 2 + q;                                                \
        int byte = (buf) * ABUF + sa_row * 128 + ((p ^ (sa_row & 7)) * 16);     \
        *reinterpret_cast<uint4*>((char*)As + byte) =                           \
            *reinterpret_cast<const uint4*>(tmp);                               \
    }

#define COMPUTE(buf)                                                            \
    _Pragma("unroll")                                                           \
    for (int s = 0; s < 2; ++s) {                                               \
        int g = s * 4 + g16;                                                    \
        bf16x8 af[2], bfr[4];                                                   \
        _Pragma("unroll")                                                       \
        for (int mi = 0; mi < 2; ++mi) {                                        \
            int row = wrb + mi * 16 + lrow;                                     \
            int byte = (buf) * ABUF + row * 128 + ((g ^ (row & 7)) * 16);       \
            af[mi] = *reinterpret_cast<const bf16x8*>((const char*)As + byte);  \
        }                                                                       \
        _Pragma("unroll")                                                       \
        for (int ni = 0; ni < 4; ++ni) {                                        \
            int col = wcb + ni * 16 + lrow;                                     \
            int byte = (buf) * BBUF + col * 128 + ((g ^ (col & 7)) * 16);       \
            bfr[ni] = *reinterpret_cast<const bf16x8*>((const char*)Bs + byte); \
        }                                                                       \
        _Pragma("unroll")                                                       \
        for (int mi = 0; mi < 2; ++mi)                                          \
            _Pragma("unroll")                                                   \
            for (int ni = 0; ni < 4; ++ni)                                      \
                acc[mi][ni] = __builtin_amdgcn_mfma_f32_16x16x32_bf16(          \
                    af[mi], bfr[ni], acc[mi][ni], 0, 0, 0);                     \
    }

    // ---- prologue: stage K-step 0 into buf 0 ----
    STAGE_B(0, 0)
    {
        float4 v[4];
        LOAD_X(0, v)
        WRITE_A(0, v)
    }
    __syncthreads();

    // ---- 2-phase main loop ----
    #pragma unroll 2
    for (int t = 0; t < NT; ++t) {
        int cur = t & 1;
        float4 v[4];
        if (t < NT - 1) {
            STAGE_B(cur ^ 1, t + 1)      // issued before compute -> hidden
            LOAD_X(t + 1, v)             // global->reg, consumed post-compute
        }
        COMPUTE(cur)
        if (t < NT - 1) {
            WRITE_A(cur ^ 1, v)          // convert + swizzled ds_write
            __syncthreads();             // compiler drain lands AFTER compute
        }
    }

    // epilogue: D row = (lane>>4)*4 + rr, col = lane&15
    int rgrp = g16 * 4;
    #pragma unroll
    for (int mi = 0; mi < 2; ++mi) {
        #pragma unroll
        for (int rr = 0; rr < 4; ++rr) {
            int lr = wrb + mi * 16 + rgrp + rr;
            int gr = rids[lr];
            if (gr >= 0) {
                float* dst = out + (size_t)gr * OUT_DIM + c0 + wcb;
                #pragma unroll
                for (int ni = 0; ni < 4; ++ni)
                    dst[ni * 16 + lrow] = acc[mi][ni][rr];
            }
        }
    }
}

extern "C" void kernel_launch(void* const* d_in, const int* in_sizes, int n_in,
                              void* d_out, int out_size, void* d_ws, size_t ws_size,
                              hipStream_t stream) {
    const float* x      = (const float*)d_in[0];
    const int*   x_type = (const int*)d_in[1];
    const float* W      = (const float*)d_in[2];
    float* out          = (float*)d_out;

    char* ws = (char*)d_ws;
    size_t off_rids = 256;
    size_t off_wt   = off_rids + sizeof(int) * (NB * 64);
    int* meta    = (int*)ws;
    int* row_ids = (int*)(ws + off_rids);
    ushort* Wt   = (ushort*)(ws + off_wt);                  // 4 MB bf16

    k_init<<<1, 64, 0, stream>>>(meta);
    k_hist<<<N_ROWS / 256, 256, 0, stream>>>(x_type, meta);
    k_scan<<<1, 64, 0, stream>>>(meta);
    hipMemsetAsync(row_ids, 0xFF, sizeof(int) * (NB * 64), stream);
    k_fill<<<N_ROWS / 256, 256, 0, stream>>>(x_type, meta, row_ids);

    dim3 wgrid(N_TYPES, K_DIM / 64, OUT_DIM / 64);
    k_wt<<<wgrid, 256, 0, stream>>>(W, Wt);

    // row-blocks fastest: the 4 column passes over x (64 MB, L3-fits)
    // come a full pass apart -> L3-absorbed (r10/r12 evidence: 85 MB FETCH)
    dim3 ggrid(NB, OUT_DIM / BN);
    k_gemm12<<<ggrid, 256, 0, stream>>>(x, Wt, meta, row_ids, out);
}

// Round 14
// 62.119 us; speedup vs baseline: 1.9537x; 1.3046x over previous
//
#include <hip/hip_runtime.h>
#include <hip/hip_bf16.h>

#define N_ROWS 32768
#define K_DIM 512
#define OUT_DIM 512
#define N_TYPES 8
#define BM 64
#define BN 256
#define BK 64
#define TPB 512             // row-tiles per type (fixed segment: 512*64 = N)

typedef __attribute__((ext_vector_type(8))) short bf16x8;
typedef __attribute__((ext_vector_type(4))) float f32x4;

__device__ inline ushort f2bf(float f) {
    __hip_bfloat16 h = __float2bfloat16(f);
    return *reinterpret_cast<ushort*>(&h);
}

__device__ inline void gload_lds16(const void* g, void* l) {
    __builtin_amdgcn_global_load_lds(
        (const __attribute__((address_space(1))) void*)g,
        (__attribute__((address_space(3))) void*)l, 16, 0, 0);
}

// meta[0..7] = per-type cursors; final value after k_fill = per-type count.
// row_ids: fixed 1-MB layout, segment t at [t*N_ROWS, t*N_ROWS + count_t),
// remainder stays -1 (memset 0xFF).
__global__ void k_fill(const int* __restrict__ x_type, int* meta, int* __restrict__ row_ids) {
    __shared__ int lcnt[N_TYPES];
    __shared__ int lbase[N_TYPES];
    if (threadIdx.x < N_TYPES) lcnt[threadIdx.x] = 0;
    __syncthreads();
    int i = blockIdx.x * 256 + threadIdx.x;
    int t = x_type[i];
    int lpos = atomicAdd(&lcnt[t], 1);
    __syncthreads();
    if (threadIdx.x < N_TYPES)
        lbase[threadIdx.x] = (lcnt[threadIdx.x] > 0)
            ? atomicAdd(&meta[threadIdx.x], lcnt[threadIdx.x]) : 0;
    __syncthreads();
    row_ids[(size_t)t * N_ROWS + lbase[t] + lpos] = i;
}

// W[t][k][c] fp32 -> Wt[t][c][k] bf16   (64x64 tiles through LDS)
__global__ void k_wt(const float* __restrict__ W, ushort* __restrict__ Wt) {
    __shared__ float tile[64][65];
    int t = blockIdx.x, kb = blockIdx.y, cb = blockIdx.z;
    const float* src = W + (size_t)t * K_DIM * OUT_DIM + (size_t)kb * 64 * OUT_DIM + cb * 64;
    #pragma unroll
    for (int j = 0; j < 16; ++j) {
        int idx = threadIdx.x + j * 256;
        int r = idx >> 6, c = idx & 63;
        tile[r][c] = src[(size_t)r * OUT_DIM + c];
    }
    __syncthreads();
    ushort* dst = Wt + (size_t)t * OUT_DIM * K_DIM + (size_t)(cb * 64) * K_DIM + kb * 64;
    #pragma unroll
    for (int j = 0; j < 16; ++j) {
        int idx = threadIdx.x + j * 256;
        int cc = idx >> 6, kk = idx & 63;
        dst[(size_t)cc * K_DIM + kk] = f2bf(tile[kk][cc]);
    }
}

// Round-6 kernel (proven 55.6 us) with: (512,4) launch bounds (VGPR cap 128,
// kernel needs ~80 -> no spill) and direct b -> (type, tile) mapping over the
// fixed row_ids segments (empty tiles early-exit; r3 proved these are free).
// 64x256 tile, 8 waves (each 32x64 out, acc[2][4]), BK=64 single-buffered,
// LDS 40.5 KB -> 3 blocks/CU.  Involution swizzle (proven 0 conflicts):
// granule g ^= (id&7) within 128-B rows; B staged by global_load_lds with the
// involution folded into the per-lane SOURCE (linear dest, rule #21);
// A reg-staged fp32->bf16 (8 elems/thread) with swizzled ds_write.
__global__ __launch_bounds__(512, 4) void k_gemm13(
    const float* __restrict__ x, const ushort* __restrict__ Wt,
    const int* __restrict__ meta, const int* __restrict__ row_ids,
    float* __restrict__ out) {

    __shared__ ushort As[BM * BK];   // 8192 B,  [row][64k], 128 B/row
    __shared__ ushort Bs[BN * BK];   // 32768 B, [col][64k], 128 B/col-row
    __shared__ int rids[BM];

    int b = blockIdx.x;              // 0..4095; row-tiles fastest
    int type = b >> 9;
    int r0 = (b & (TPB - 1)) * BM;
    if (r0 >= meta[type]) return;    // empty tile

    int tid = threadIdx.x;
    int wave = tid >> 6, lane = tid & 63;

    if (tid < BM) rids[tid] = row_ids[(size_t)type * N_ROWS + r0 + tid];
    __syncthreads();

    int c0 = blockIdx.y * BN;
    const ushort* Wtt = Wt + (size_t)type * OUT_DIM * K_DIM + (size_t)c0 * K_DIM;

    // ---- A staging role: 8 threads/row, 8 elems (32 B fp32) each ----
    int sa_row  = tid >> 3;
    int sa_slot = tid & 7;           // 16-B bf16 granule within 128-B row
    int sa_rid  = rids[sa_row];
    const float* sa_src = x + (size_t)max(sa_rid, 0) * K_DIM + sa_slot * 8;
    int sa_byte = (sa_row * 128 + sa_slot * 16) ^ ((sa_row & 7) << 4);

    // ---- B staging role: chunk = 8 cols x 128 B (1 KB); lane -> (col,pos);
    //      source granule = pos ^ (col&7)  (involution on SOURCE) ----
    int sb_colgrp = lane >> 3;                               // 0..7
    int sb_koff   = (((lane & 7) * 16) ^ (sb_colgrp << 4)) >> 1;  // elems

    int wrb = (wave >> 2) * 32;      // wave row base (0/32)
    int wcb = (wave & 3) * 64;       // wave col base (0..192)
    int lrow = lane & 15;
    int lkb16 = (lane >> 4) * 16;    // 16-B k-fragment offset

    f32x4 acc[2][4] = {};

    #pragma unroll 1
    for (int kk = 0; kk < K_DIM; kk += BK) {
        // stage B: 4 chunks/wave, 1 KB each (8 cols x 128 B)
        #pragma unroll
        for (int j = 0; j < 4; ++j) {
            int chunk = wave * 4 + j;
            int col = chunk * 8 + sb_colgrp;
            gload_lds16(Wtt + (size_t)col * K_DIM + kk + sb_koff,
                        (char*)Bs + chunk * 1024);
        }
        // stage A: load 8 fp32, convert, swizzled ds_write
        {
            ushort tmp[8] = {0, 0, 0, 0, 0, 0, 0, 0};
            if (sa_rid >= 0) {
                float4 v0 = *reinterpret_cast<const float4*>(sa_src + kk);
                float4 v1 = *reinterpret_cast<const float4*>(sa_src + kk + 4);
                tmp[0] = f2bf(v0.x); tmp[1] = f2bf(v0.y); tmp[2] = f2bf(v0.z); tmp[3] = f2bf(v0.w);
                tmp[4] = f2bf(v1.x); tmp[5] = f2bf(v1.y); tmp[6] = f2bf(v1.z); tmp[7] = f2bf(v1.w);
            }
            *reinterpret_cast<uint4*>((char*)As + sa_byte) = *reinterpret_cast<const uint4*>(tmp);
        }
        __syncthreads();

        #pragma unroll
        for (int s = 0; s < 2; ++s) {
            bf16x8 af[2], bfr[4];
            #pragma unroll
            for (int mi = 0; mi < 2; ++mi) {
                int row = wrb + mi * 16 + lrow;
                int byte = (row * 128 + s * 64 + lkb16) ^ ((row & 7) << 4);
                af[mi] = *reinterpret_cast<const bf16x8*>((const char*)As + byte);
            }
            #pragma unroll
            for (int ni = 0; ni < 4; ++ni) {
                int col = wcb + ni * 16 + lrow;
                int byte = (col * 128 + s * 64 + lkb16) ^ ((col & 7) << 4);
                bfr[ni] = *reinterpret_cast<const bf16x8*>((const char*)Bs + byte);
            }
            #pragma unroll
            for (int mi = 0; mi < 2; ++mi)
                #pragma unroll
                for (int ni = 0; ni < 4; ++ni)
                    acc[mi][ni] = __builtin_amdgcn_mfma_f32_16x16x32_bf16(
                        af[mi], bfr[ni], acc[mi][ni], 0, 0, 0);
        }
        __syncthreads();
    }

    // epilogue: D row = (lane>>4)*4 + rr, col = lane&15
    int rgrp = (lane >> 4) * 4;
    #pragma unroll
    for (int mi = 0; mi < 2; ++mi) {
        #pragma unroll
        for (int rr = 0; rr < 4; ++rr) {
            int lr = wrb + mi * 16 + rgrp + rr;
            int gr = rids[lr];
            if (gr >= 0) {
                float* dst = out + (size_t)gr * OUT_DIM + c0 + wcb;
                #pragma unroll
                for (int ni = 0; ni < 4; ++ni)
                    dst[ni * 16 + lrow] = acc[mi][ni][rr];
            }
        }
    }
}

extern "C" void kernel_launch(void* const* d_in, const int* in_sizes, int n_in,
                              void* d_out, int out_size, void* d_ws, size_t ws_size,
                              hipStream_t stream) {
    const float* x      = (const float*)d_in[0];
    const int*   x_type = (const int*)d_in[1];
    const float* W      = (const float*)d_in[2];
    float* out          = (float*)d_out;

    // ws layout: meta (256 B) | row_ids (8*N ints = 1 MB) | Wt (4 MB bf16)
    char* ws = (char*)d_ws;
    size_t off_rids = 256;
    size_t off_wt   = off_rids + sizeof(int) * (size_t)N_TYPES * N_ROWS;
    int* meta    = (int*)ws;
    int* row_ids = (int*)(ws + off_rids);
    ushort* Wt   = (ushort*)(ws + off_wt);

    hipMemsetAsync(meta, 0, sizeof(int) * N_TYPES, stream);
    hipMemsetAsync(row_ids, 0xFF, sizeof(int) * (size_t)N_TYPES * N_ROWS, stream);
    k_fill<<<N_ROWS / 256, 256, 0, stream>>>(x_type, meta, row_ids);

    dim3 wgrid(N_TYPES, K_DIM / 64, OUT_DIM / 64);
    k_wt<<<wgrid, 256, 0, stream>>>(W, Wt);

    // row-tiles fastest: the second column pass over x comes a full pass
    // later -> L3-absorbed (r6/r10/r12 evidence: ~85 MB FETCH)
    dim3 ggrid(N_TYPES * TPB, OUT_DIM / BN);
    k_gemm13<<<ggrid, 512, 0, stream>>>(x, Wt, meta, row_ids, out);
}